// Round 2
// 780.778 us; speedup vs baseline: 1.3359x; 1.3359x over previous
//
#include <hip/hip_runtime.h>
#include <math.h>

// Problem constants
#define T_TOK 65536
#define D_DIM 2048
#define E_EXP 128
#define K_TOP 4
#define GS    64   // experts per group (G=2)

// GEMM config: BM=BN=128, 4 waves, wave tile 64x64, mfma_f32_16x16x32_f16
#define BM   128
#define BK   32                 // f32 k per LDS chunk (= one MFMA K per pass)
#define NCH  (D_DIM / BK)       // 64 chunks
#define LROW 129                // logits LDS row stride: (t*129+e)%32 covers all banks

// Split-f16 precision scheme: x and W pre-scaled by 2^8 (exact) so the f16
// residual planes are in NORMAL f16 range (no subnormal-flush hazard in MFMA).
// logits recovered with one multiply by 2^-16 at the epilogue.
#define XSCALE 256.0f
#define WSCALE 256.0f
#define OSCALE (1.0f / 65536.0f)

#define WS_BYTES ((size_t)E_EXP * D_DIM * 2 /*planes*/ * 2 /*B per f16*/)  // 1 MiB

typedef _Float16 f16x8 __attribute__((ext_vector_type(8)));
typedef float    f32x4 __attribute__((ext_vector_type(4)));
typedef unsigned short u16;

__device__ __forceinline__ void gload_lds16(const void* g, void* l) {
  __builtin_amdgcn_global_load_lds(
      (const __attribute__((address_space(1))) unsigned int*)g,
      (__attribute__((address_space(3))) unsigned int*)l, 16, 0, 0);
}

// ---------------------------------------------------------------------------
// prep: split f32 W[E][D] into f16 hi/lo planes (scaled by 2^8), laid out per
// 32-k chunk in exact MFMA B-fragment block order so the main kernel stages it
// with global_load_lds. Per chunk (16KB): 16B blocks [plane(2)][ntile(8)][l],
// where block lane l = ks*16 + r16 holds W[e = ntile*16+r16][k = c*32+ks*8+j].
// Total ws: 64 chunks * 16KB = 1 MiB.
// ---------------------------------------------------------------------------
__global__ __launch_bounds__(256) void prep_w(const float* __restrict__ W,
                                              u16* __restrict__ wsB) {
  const int gid = blockIdx.x * 256 + threadIdx.x;  // = e*256 + k0/8
  const int e   = gid >> 8;
  const int k0  = (gid & 255) << 3;
  const int c   = k0 >> 5;
  const int ks  = (k0 >> 3) & 3;
  const int n16 = e >> 4, r16 = e & 15;
  const float* wp = W + (size_t)e * D_DIM + k0;
  float4 w0 = *(const float4*)(wp);
  float4 w1 = *(const float4*)(wp + 4);
  const float f[8] = {w0.x, w0.y, w0.z, w0.w, w1.x, w1.y, w1.z, w1.w};
  f16x8 hv, lv;
#pragma unroll
  for (int j = 0; j < 8; ++j) {
    float s = f[j] * WSCALE;
    _Float16 h = (_Float16)s;
    hv[j] = h;
    lv[j] = (_Float16)(s - (float)h);
  }
  u16* dst = wsB + (size_t)c * 8192 + (size_t)(n16 * 64 + ks * 16 + r16) * 8;
  *(f16x8*)(dst)        = hv;
  *(f16x8*)(dst + 4096) = lv;   // lo plane: +512 blocks
}

// ---------------------------------------------------------------------------
// Fused split-f16 MFMA GEMM (logits = x@W.T, ~1.5e-7 logit error) + gating.
// USE_WS=true : B staged from the pre-split ws image via global_load_lds.
// USE_WS=false: no-workspace fallback — B reg-staged from W with in-kernel
//               split (same thread decomposition and LDS layout as A).
// ---------------------------------------------------------------------------
template <bool USE_WS>
__global__ __launch_bounds__(256, 2) void gemm_gate(
    const float* __restrict__ x, const float* __restrict__ W,
    const u16* __restrict__ wsB, const float* __restrict__ bias,
    float* __restrict__ w_out, float* __restrict__ idx_out) {
  // union region: K-loop uses [0,32KB) as A/B fragment tiles; epilogue reuses
  // the whole buffer as the 128 x 129 f32 logits tile.
  __shared__ __align__(16) unsigned char smem[BM * LROW * 4];  // 66048 B
  __shared__ float bias_lds[E_EXP];
  u16*   As = (u16*)smem;            // 16KB: blocks [plane(2)][mtile(8)][ks*16+r16]
  u16*   Bs = (u16*)(smem + 16384);  // 16KB: same structure, expert tiles
  float* Ls = (float*)smem;          // epilogue logits [128][129]

  const int tid = threadIdx.x;
  const int l   = tid & 63;
  const int wid = tid >> 6;
  const int wm  = wid >> 1;          // wave token-half  (64 rows)
  const int wn  = wid & 1;           // wave expert-half (64 cols)
  const int lu  = l * 8;             // fragment lane offset (u16 units = 16B)

  if (tid < E_EXP) bias_lds[tid] = bias[tid];

  // staging role: one row (token for A / expert for B) + one 16-k half each
  const int row = tid >> 1;          // 0..127
  const int kh  = tid & 1;           // 0,1
  const int m16 = row >> 4, r16 = row & 15;
  const int aw  = (m16 * 64 + kh * 32 + r16) * 8;  // hi plane, ks=2*kh
  const float* xp = x + (size_t)(blockIdx.x * BM + row) * D_DIM + kh * 16;
  const float* wp = W + (size_t)row * D_DIM + kh * 16;  // fallback path only

  f32x4 acc[4][4], sh[4][4];
  const f32x4 vzero = {0.f, 0.f, 0.f, 0.f};
#pragma unroll
  for (int i = 0; i < 4; ++i)
#pragma unroll
    for (int j = 0; j < 4; ++j) { acc[i][j] = vzero; sh[i][j] = vzero; }

  // prefetch chunk 0
  float4 xv0 = *(const float4*)(xp);
  float4 xv1 = *(const float4*)(xp + 4);
  float4 xv2 = *(const float4*)(xp + 8);
  float4 xv3 = *(const float4*)(xp + 12);
  float4 wv0, wv1, wv2, wv3;
  if constexpr (!USE_WS) {
    wv0 = *(const float4*)(wp);
    wv1 = *(const float4*)(wp + 4);
    wv2 = *(const float4*)(wp + 8);
    wv3 = *(const float4*)(wp + 12);
  }

  for (int c = 0; c < NCH; ++c) {
    __syncthreads();  // previous chunk's fragment reads done

    // ---- stage A: 16 f32 -> f16 hi/lo (scaled), 4x16B writes, fragment order
    {
      const float f[16] = {xv0.x, xv0.y, xv0.z, xv0.w, xv1.x, xv1.y, xv1.z, xv1.w,
                           xv2.x, xv2.y, xv2.z, xv2.w, xv3.x, xv3.y, xv3.z, xv3.w};
      f16x8 h0, h1, l0, l1;
#pragma unroll
      for (int j = 0; j < 8; ++j) {
        float sa = f[j] * XSCALE;
        _Float16 ha = (_Float16)sa;
        h0[j] = ha; l0[j] = (_Float16)(sa - (float)ha);
        float sb = f[j + 8] * XSCALE;
        _Float16 hb = (_Float16)sb;
        h1[j] = hb; l1[j] = (_Float16)(sb - (float)hb);
      }
      *(f16x8*)(As + aw)        = h0;
      *(f16x8*)(As + aw + 128)  = h1;   // ks+1 -> +16 blocks
      *(f16x8*)(As + aw + 4096) = l0;   // lo plane -> +512 blocks
      *(f16x8*)(As + aw + 4224) = l1;
    }

    // ---- stage B
    if constexpr (USE_WS) {
      // direct global->LDS copy of pre-split W chunk image (16KB)
      const u16* src = wsB + (size_t)c * 8192 + tid * 8;
      u16* dst = Bs + tid * 8;
#pragma unroll
      for (int i = 0; i < 4; ++i)
        gload_lds16(src + i * 2048, dst + i * 2048);
    } else {
      // fallback: in-kernel split of W (expert row = `row`), same layout as A
      const float f[16] = {wv0.x, wv0.y, wv0.z, wv0.w, wv1.x, wv1.y, wv1.z, wv1.w,
                           wv2.x, wv2.y, wv2.z, wv2.w, wv3.x, wv3.y, wv3.z, wv3.w};
      f16x8 h0, h1, l0, l1;
#pragma unroll
      for (int j = 0; j < 8; ++j) {
        float sa = f[j] * WSCALE;
        _Float16 ha = (_Float16)sa;
        h0[j] = ha; l0[j] = (_Float16)(sa - (float)ha);
        float sb = f[j + 8] * WSCALE;
        _Float16 hb = (_Float16)sb;
        h1[j] = hb; l1[j] = (_Float16)(sb - (float)hb);
      }
      *(f16x8*)(Bs + aw)        = h0;
      *(f16x8*)(Bs + aw + 128)  = h1;
      *(f16x8*)(Bs + aw + 4096) = l0;
      *(f16x8*)(Bs + aw + 4224) = l1;
    }

    __syncthreads();  // A/B written; gload_lds drained by barrier's vmcnt wait

    if (c + 1 < NCH) {  // register prefetch of next chunk overlaps compute
      const float* xn = xp + (c + 1) * 32;
      xv0 = *(const float4*)(xn);
      xv1 = *(const float4*)(xn + 4);
      xv2 = *(const float4*)(xn + 8);
      xv3 = *(const float4*)(xn + 12);
      if constexpr (!USE_WS) {
        const float* wn_ = wp + (c + 1) * 32;
        wv0 = *(const float4*)(wn_);
        wv1 = *(const float4*)(wn_ + 4);
        wv2 = *(const float4*)(wn_ + 8);
        wv3 = *(const float4*)(wn_ + 12);
      }
    }

    // ---- compute: 16 16x16 tiles x 3 passes (hh, hl, lh), lane-linear reads
    f16x8 Ah[4], Al[4];
#pragma unroll
    for (int m_ = 0; m_ < 4; ++m_) {
      const int mt = wm * 4 + m_;
      Ah[m_] = *(const f16x8*)(As + mt * 512 + lu);
      Al[m_] = *(const f16x8*)(As + 4096 + mt * 512 + lu);
    }
#pragma unroll
    for (int n_ = 0; n_ < 4; ++n_) {
      const int nt = wn * 4 + n_;
      f16x8 Bh = *(const f16x8*)(Bs + nt * 512 + lu);
      f16x8 Bl = *(const f16x8*)(Bs + 4096 + nt * 512 + lu);
#pragma unroll
      for (int m_ = 0; m_ < 4; ++m_) {
        acc[m_][n_] = __builtin_amdgcn_mfma_f32_16x16x32_f16(Ah[m_], Bh, acc[m_][n_], 0, 0, 0);
        acc[m_][n_] = __builtin_amdgcn_mfma_f32_16x16x32_f16(Ah[m_], Bl, acc[m_][n_], 0, 0, 0);
        acc[m_][n_] = __builtin_amdgcn_mfma_f32_16x16x32_f16(Al[m_], Bh, acc[m_][n_], 0, 0, 0);
      }
    }

    // f32 shadow drain every 128 k: keeps accumulation error ~1.4e-7
    if ((c & 3) == 3) {
#pragma unroll
      for (int i = 0; i < 4; ++i)
#pragma unroll
        for (int j = 0; j < 4; ++j) { sh[i][j] += acc[i][j]; acc[i][j] = vzero; }
    }
  }

  __syncthreads();  // staging region becomes the logits tile

  // epilogue 1: logits -> LDS. D frag: col = l&15, row = (l>>4)*4 + q.
#pragma unroll
  for (int m_ = 0; m_ < 4; ++m_) {
#pragma unroll
    for (int n_ = 0; n_ < 4; ++n_) {
      const int gcol  = wn * 64 + n_ * 16 + (l & 15);
      const int grow0 = wm * 64 + m_ * 16 + ((l >> 4) << 2);
#pragma unroll
      for (int q = 0; q < 4; ++q)
        Ls[(grow0 + q) * LROW + gcol] = sh[m_][n_][q] * OSCALE;
    }
  }
  __syncthreads();

  // epilogue 2: one thread per token, group-limited top-4 (unchanged logic;
  // bias added at read time). Softmax denominator cancels.
  if (tid < BM) {
    const float* rowp = Ls + tid * LROW;

    float m1[2], m2[2];
#pragma unroll
    for (int g = 0; g < 2; ++g) {
      m1[g] = -INFINITY;
      m2[g] = -INFINITY;
      for (int e = 0; e < GS; ++e) {
        float v = rowp[g * GS + e] + bias_lds[g * GS + e];
        if (v > m1[g]) { m2[g] = m1[g]; m1[g] = v; }
        else if (v > m2[g]) { m2[g] = v; }
      }
    }
    float M  = fmaxf(m1[0], m1[1]);
    float r0 = expf(m1[0] - M) + expf(m2[0] - M);
    float r1 = expf(m1[1] - M) + expf(m2[1] - M);
    int g = (r1 > r0) ? 1 : 0;  // tie -> lower group index

    float v4[4] = {-INFINITY, -INFINITY, -INFINITY, -INFINITY};
    int i4[4] = {0, 0, 0, 0};
    const int base = g * GS;
    for (int e = 0; e < GS; ++e) {
      float v = rowp[base + e] + bias_lds[base + e];
      if (v > v4[3]) {
        if (v > v4[1]) {
          if (v > v4[0]) {
            v4[3] = v4[2]; i4[3] = i4[2];
            v4[2] = v4[1]; i4[2] = i4[1];
            v4[1] = v4[0]; i4[1] = i4[0];
            v4[0] = v; i4[0] = e;
          } else {
            v4[3] = v4[2]; i4[3] = i4[2];
            v4[2] = v4[1]; i4[2] = i4[1];
            v4[1] = v; i4[1] = e;
          }
        } else {
          if (v > v4[2]) {
            v4[3] = v4[2]; i4[3] = i4[2];
            v4[2] = v; i4[2] = e;
          } else {
            v4[3] = v; i4[3] = e;
          }
        }
      }
    }

    float s[4], sum = 0.0f;
#pragma unroll
    for (int j = 0; j < 4; ++j) { s[j] = expf(v4[j] - M); sum += s[j]; }
    float denom = fmaxf(sum, 1e-9f);
    const int t = blockIdx.x * BM + tid;
#pragma unroll
    for (int j = 0; j < 4; ++j) {
      w_out[(size_t)t * K_TOP + j]   = s[j] / denom;
      idx_out[(size_t)t * K_TOP + j] = (float)(base + i4[j]);
    }
  }
}

extern "C" void kernel_launch(void* const* d_in, const int* in_sizes, int n_in,
                              void* d_out, int out_size, void* d_ws, size_t ws_size,
                              hipStream_t stream) {
  (void)in_sizes; (void)n_in; (void)out_size;
  const float* x    = (const float*)d_in[0];
  const float* W    = (const float*)d_in[1];
  const float* bias = (const float*)d_in[2];
  float* out = (float*)d_out;

  const bool use_ws = (d_ws != nullptr) && (ws_size >= WS_BYTES);
  if (use_ws) {
    u16* wsB = (u16*)d_ws;
    prep_w<<<E_EXP, 256, 0, stream>>>(W, wsB);
    gemm_gate<true><<<T_TOK / BM, 256, 0, stream>>>(
        x, W, wsB, bias, out, out + (size_t)T_TOK * K_TOP);
  } else {
    gemm_gate<false><<<T_TOK / BM, 256, 0, stream>>>(
        x, W, nullptr, bias, out, out + (size_t)T_TOK * K_TOP);
  }
}

// Round 3
// 768.304 us; speedup vs baseline: 1.3576x; 1.0162x over previous
//
#include <hip/hip_runtime.h>
#include <math.h>

// Problem constants
#define T_TOK 65536
#define D_DIM 2048
#define E_EXP 128
#define K_TOP 4
#define GS    64   // experts per group (G=2)

// GEMM config: BM=BN=128, 4 waves, wave tile 64x64, mfma_f32_16x16x32_f16
#define BM   128
#define BK   32                 // f32 k per LDS chunk
#define NCH  (D_DIM / BK)       // 64 chunks
#define LROW 129                // logits LDS row stride

// Split-f16 precision scheme: x and W pre-scaled by 2^8 (exact) so the f16
// residual planes are in NORMAL f16 range. One multiply by 2^-16 at epilogue.
#define XSCALE 256.0f
#define WSCALE 256.0f
#define OSCALE (1.0f / 65536.0f)

#define WS_BYTES ((size_t)E_EXP * D_DIM * 2 /*planes*/ * 2 /*B per f16*/)  // 1 MiB

typedef _Float16 f16x8 __attribute__((ext_vector_type(8)));
typedef float    f32x4 __attribute__((ext_vector_type(4)));
typedef unsigned short u16;

__device__ __forceinline__ void gload_lds16(const void* g, void* l) {
  __builtin_amdgcn_global_load_lds(
      (const __attribute__((address_space(1))) unsigned int*)g,
      (__attribute__((address_space(3))) unsigned int*)l, 16, 0, 0);
}

// ---------------------------------------------------------------------------
// prep: split f32 W[E][D] into f16 hi/lo planes (scaled by 2^8), laid out per
// 32-k chunk in exact MFMA B-fragment block order. Per chunk (16KB): 16B
// blocks [plane(2)][ntile(8)][l], block lane l = ks*16 + r16 holds
// W[e = ntile*16+r16][k = c*32+ks*8+j]. Total ws: 64 chunks * 16KB = 1 MiB.
// ---------------------------------------------------------------------------
__global__ __launch_bounds__(256) void prep_w(const float* __restrict__ W,
                                              u16* __restrict__ wsB) {
  const int gid = blockIdx.x * 256 + threadIdx.x;  // = e*256 + k0/8
  const int e   = gid >> 8;
  const int k0  = (gid & 255) << 3;
  const int c   = k0 >> 5;
  const int ks  = (k0 >> 3) & 3;
  const int n16 = e >> 4, r16 = e & 15;
  const float* wp = W + (size_t)e * D_DIM + k0;
  float4 w0 = *(const float4*)(wp);
  float4 w1 = *(const float4*)(wp + 4);
  const float f[8] = {w0.x, w0.y, w0.z, w0.w, w1.x, w1.y, w1.z, w1.w};
  f16x8 hv, lv;
#pragma unroll
  for (int j = 0; j < 8; ++j) {
    float s = f[j] * WSCALE;
    _Float16 h = (_Float16)s;
    hv[j] = h;
    lv[j] = (_Float16)(s - (float)h);
  }
  u16* dst = wsB + (size_t)c * 8192 + (size_t)(n16 * 64 + ks * 16 + r16) * 8;
  *(f16x8*)(dst)        = hv;
  *(f16x8*)(dst + 4096) = lv;   // lo plane: +512 blocks
}

// stage 16 f32 -> f16 hi/lo planes (scaled) in fragment block order.
__device__ __forceinline__ void stage16(u16* dst, int aw, const float4& v0,
                                        const float4& v1, const float4& v2,
                                        const float4& v3, float scale) {
  const float f[16] = {v0.x, v0.y, v0.z, v0.w, v1.x, v1.y, v1.z, v1.w,
                       v2.x, v2.y, v2.z, v2.w, v3.x, v3.y, v3.z, v3.w};
  f16x8 h0, h1, l0, l1;
#pragma unroll
  for (int j = 0; j < 8; ++j) {
    float sa = f[j] * scale;
    _Float16 ha = (_Float16)sa;
    h0[j] = ha; l0[j] = (_Float16)(sa - (float)ha);
    float sb = f[j + 8] * scale;
    _Float16 hb = (_Float16)sb;
    h1[j] = hb; l1[j] = (_Float16)(sb - (float)hb);
  }
  *(f16x8*)(dst + aw)        = h0;
  *(f16x8*)(dst + aw + 128)  = h1;   // ks+1 -> +16 blocks
  *(f16x8*)(dst + aw + 4096) = l0;   // lo plane -> +512 blocks
  *(f16x8*)(dst + aw + 4224) = l1;
}

// one 32-k chunk of MFMA: 16 16x16 tiles x 3 passes (hh, hl, lh)
__device__ __forceinline__ void compute32(const u16* As_, const u16* Bs_,
                                          int wm, int wn, int lu,
                                          f32x4 (&acc)[4][4]) {
  f16x8 Ah[4], Al[4];
#pragma unroll
  for (int m_ = 0; m_ < 4; ++m_) {
    const int mt = wm * 4 + m_;
    Ah[m_] = *(const f16x8*)(As_ + mt * 512 + lu);
    Al[m_] = *(const f16x8*)(As_ + 4096 + mt * 512 + lu);
  }
#pragma unroll
  for (int n_ = 0; n_ < 4; ++n_) {
    const int nt = wn * 4 + n_;
    f16x8 Bh = *(const f16x8*)(Bs_ + nt * 512 + lu);
    f16x8 Bl = *(const f16x8*)(Bs_ + 4096 + nt * 512 + lu);
#pragma unroll
    for (int m_ = 0; m_ < 4; ++m_) {
      acc[m_][n_] = __builtin_amdgcn_mfma_f32_16x16x32_f16(Ah[m_], Bh, acc[m_][n_], 0, 0, 0);
      acc[m_][n_] = __builtin_amdgcn_mfma_f32_16x16x32_f16(Ah[m_], Bl, acc[m_][n_], 0, 0, 0);
      acc[m_][n_] = __builtin_amdgcn_mfma_f32_16x16x32_f16(Al[m_], Bh, acc[m_][n_], 0, 0, 0);
    }
  }
}

// ---------------------------------------------------------------------------
// Fused split-f16 MFMA GEMM + gating, double-buffered single-barrier pipeline
// (catalog T3-minimum 2-phase): STAGE(c+1) issued before compute(c); one
// __syncthreads per chunk; gload/x latency hides under the MFMA phase.
// ---------------------------------------------------------------------------
template <bool USE_WS>
__global__ __launch_bounds__(256, 2) void gemm_gate(
    const float* __restrict__ x, const float* __restrict__ W,
    const u16* __restrict__ wsB, const float* __restrict__ bias,
    float* __restrict__ w_out, float* __restrict__ idx_out) {
  // union: K-loop uses [0,64KB) as 2x(A,B) fragment buffers; epilogue reuses
  // the whole region as the 128 x 129 f32 logits tile.
  __shared__ __align__(16) unsigned char smem[BM * LROW * 4];  // 66048 B
  __shared__ float bias_lds[E_EXP];
  u16* As0 = (u16*)smem;          // each buffer: 8192 u16 = 16 KB
  u16* As1 = As0 + 8192;
  u16* Bs0 = As0 + 16384;
  u16* Bs1 = As0 + 24576;
  float* Ls = (float*)smem;       // epilogue logits [128][129]

  const int tid = threadIdx.x;
  const int l   = tid & 63;
  const int wid = tid >> 6;
  const int wm  = wid >> 1;       // wave token-half
  const int wn  = wid & 1;        // wave expert-half
  const int lu  = l * 8;          // fragment lane offset (u16 units = 16B)

  if (tid < E_EXP) bias_lds[tid] = bias[tid];

  // staging role: one row (token for A / expert for B) + one 16-k half each
  const int row = tid >> 1;       // 0..127
  const int kh  = tid & 1;        // 0,1
  const int m16 = row >> 4, r16 = row & 15;
  const int aw  = (m16 * 64 + kh * 32 + r16) * 8;
  const float* xp = x + (size_t)(blockIdx.x * BM + row) * D_DIM + kh * 16;
  const float* wp = W + (size_t)row * D_DIM + kh * 16;  // fallback only

  f32x4 acc[4][4], sh[4][4];
  const f32x4 vzero = {0.f, 0.f, 0.f, 0.f};
#pragma unroll
  for (int i = 0; i < 4; ++i)
#pragma unroll
    for (int j = 0; j < 4; ++j) { acc[i][j] = vzero; sh[i][j] = vzero; }

  // x prefetch register sets: xa* = even chunks, xb* = odd chunks
  float4 xa0, xa1, xa2, xa3, xb0, xb1, xb2, xb3;
  float4 wa0, wa1, wa2, wa3, wb0, wb1, wb2, wb3;  // fallback only

  // ---- prologue: stage chunk 0 into buf0; prefetch X(1)
  {
    float4 t0 = *(const float4*)(xp);
    float4 t1 = *(const float4*)(xp + 4);
    float4 t2 = *(const float4*)(xp + 8);
    float4 t3 = *(const float4*)(xp + 12);
    stage16(As0, aw, t0, t1, t2, t3, XSCALE);
    if constexpr (USE_WS) {
      const u16* src = wsB + tid * 8;
#pragma unroll
      for (int i = 0; i < 4; ++i)
        gload_lds16(src + i * 2048, Bs0 + tid * 8 + i * 2048);
    } else {
      float4 s0 = *(const float4*)(wp);
      float4 s1 = *(const float4*)(wp + 4);
      float4 s2 = *(const float4*)(wp + 8);
      float4 s3 = *(const float4*)(wp + 12);
      stage16(Bs0, aw, s0, s1, s2, s3, WSCALE);
    }
    const float* xn = xp + BK;
    xb0 = *(const float4*)(xn);      xb1 = *(const float4*)(xn + 4);
    xb2 = *(const float4*)(xn + 8);  xb3 = *(const float4*)(xn + 12);
    if constexpr (!USE_WS) {
      const float* wn_ = wp + BK;
      wb0 = *(const float4*)(wn_);      wb1 = *(const float4*)(wn_ + 4);
      wb2 = *(const float4*)(wn_ + 8);  wb3 = *(const float4*)(wn_ + 12);
    }
  }
  __syncthreads();  // buf0 ready (drains gload vmcnt); X(1) in regs

  for (int c = 0; c < NCH; c += 2) {
    // ---- even body: compute chunk c (buf0), stage chunk c+1 (buf1)
    {
      const int cn = (c + 2 < NCH) ? c + 2 : NCH - 1;
      const float* xn = xp + cn * BK;       // issue X(c+2) into free even set
      xa0 = *(const float4*)(xn);      xa1 = *(const float4*)(xn + 4);
      xa2 = *(const float4*)(xn + 8);  xa3 = *(const float4*)(xn + 12);
      if constexpr (USE_WS) {
        const u16* src = wsB + (size_t)(c + 1) * 8192 + tid * 8;
#pragma unroll
        for (int i = 0; i < 4; ++i)
          gload_lds16(src + i * 2048, Bs1 + tid * 8 + i * 2048);
      } else {
        const float* wn_ = wp + cn * BK;
        wa0 = *(const float4*)(wn_);      wa1 = *(const float4*)(wn_ + 4);
        wa2 = *(const float4*)(wn_ + 8);  wa3 = *(const float4*)(wn_ + 12);
        stage16(Bs1, aw, wb0, wb1, wb2, wb3, WSCALE);
      }
      stage16(As1, aw, xb0, xb1, xb2, xb3, XSCALE);
      compute32(As0, Bs0, wm, wn, lu, acc);
      __syncthreads();  // buf1 ready; buf0 reads done
    }
    // ---- odd body: compute chunk c+1 (buf1), stage chunk c+2 (buf0)
    {
      const int cs = (c + 2 < NCH) ? c + 2 : NCH - 1;  // staged chunk (clamped)
      const int cl = (c + 3 < NCH) ? c + 3 : NCH - 1;
      const float* xn = xp + cl * BK;       // issue X(c+3) into free odd set
      xb0 = *(const float4*)(xn);      xb1 = *(const float4*)(xn + 4);
      xb2 = *(const float4*)(xn + 8);  xb3 = *(const float4*)(xn + 12);
      if constexpr (USE_WS) {
        const u16* src = wsB + (size_t)cs * 8192 + tid * 8;
#pragma unroll
        for (int i = 0; i < 4; ++i)
          gload_lds16(src + i * 2048, Bs0 + tid * 8 + i * 2048);
      } else {
        const float* wn_ = wp + cl * BK;
        wb0 = *(const float4*)(wn_);      wb1 = *(const float4*)(wn_ + 4);
        wb2 = *(const float4*)(wn_ + 8);  wb3 = *(const float4*)(wn_ + 12);
        stage16(Bs0, aw, wa0, wa1, wa2, wa3, WSCALE);
      }
      stage16(As0, aw, xa0, xa1, xa2, xa3, XSCALE);
      compute32(As1, Bs1, wm, wn, lu, acc);
      if (((c + 1) & 3) == 3) {  // f32 shadow drain every 128 k
#pragma unroll
        for (int i = 0; i < 4; ++i)
#pragma unroll
          for (int j = 0; j < 4; ++j) { sh[i][j] += acc[i][j]; acc[i][j] = vzero; }
      }
      __syncthreads();  // buf0 ready; buf1 reads done
    }
  }
  // loop-end barrier already separates last frag reads from Ls overwrite

  // epilogue 1: logits -> LDS. D frag: col = l&15, row = (l>>4)*4 + q.
#pragma unroll
  for (int m_ = 0; m_ < 4; ++m_) {
#pragma unroll
    for (int n_ = 0; n_ < 4; ++n_) {
      const int gcol  = wn * 64 + n_ * 16 + (l & 15);
      const int grow0 = wm * 64 + m_ * 16 + ((l >> 4) << 2);
#pragma unroll
      for (int q = 0; q < 4; ++q)
        Ls[(grow0 + q) * LROW + gcol] = sh[m_][n_][q] * OSCALE;
    }
  }
  __syncthreads();

  // epilogue 2: one thread per token, group-limited top-4 (unchanged logic).
  if (tid < BM) {
    const float* rowp = Ls + tid * LROW;

    float m1[2], m2[2];
#pragma unroll
    for (int g = 0; g < 2; ++g) {
      m1[g] = -INFINITY;
      m2[g] = -INFINITY;
      for (int e = 0; e < GS; ++e) {
        float v = rowp[g * GS + e] + bias_lds[g * GS + e];
        if (v > m1[g]) { m2[g] = m1[g]; m1[g] = v; }
        else if (v > m2[g]) { m2[g] = v; }
      }
    }
    float M  = fmaxf(m1[0], m1[1]);
    float r0 = expf(m1[0] - M) + expf(m2[0] - M);
    float r1 = expf(m1[1] - M) + expf(m2[1] - M);
    int g = (r1 > r0) ? 1 : 0;  // tie -> lower group index

    float v4[4] = {-INFINITY, -INFINITY, -INFINITY, -INFINITY};
    int i4[4] = {0, 0, 0, 0};
    const int base = g * GS;
    for (int e = 0; e < GS; ++e) {
      float v = rowp[base + e] + bias_lds[base + e];
      if (v > v4[3]) {
        if (v > v4[1]) {
          if (v > v4[0]) {
            v4[3] = v4[2]; i4[3] = i4[2];
            v4[2] = v4[1]; i4[2] = i4[1];
            v4[1] = v4[0]; i4[1] = i4[0];
            v4[0] = v; i4[0] = e;
          } else {
            v4[3] = v4[2]; i4[3] = i4[2];
            v4[2] = v4[1]; i4[2] = i4[1];
            v4[1] = v; i4[1] = e;
          }
        } else {
          if (v > v4[2]) {
            v4[3] = v4[2]; i4[3] = i4[2];
            v4[2] = v; i4[2] = e;
          } else {
            v4[3] = v; i4[3] = e;
          }
        }
      }
    }

    float s[4], sum = 0.0f;
#pragma unroll
    for (int j = 0; j < 4; ++j) { s[j] = expf(v4[j] - M); sum += s[j]; }
    float denom = fmaxf(sum, 1e-9f);
    const int t = blockIdx.x * BM + tid;
#pragma unroll
    for (int j = 0; j < 4; ++j) {
      w_out[(size_t)t * K_TOP + j]   = s[j] / denom;
      idx_out[(size_t)t * K_TOP + j] = (float)(base + i4[j]);
    }
  }
}

extern "C" void kernel_launch(void* const* d_in, const int* in_sizes, int n_in,
                              void* d_out, int out_size, void* d_ws, size_t ws_size,
                              hipStream_t stream) {
  (void)in_sizes; (void)n_in; (void)out_size;
  const float* x    = (const float*)d_in[0];
  const float* W    = (const float*)d_in[1];
  const float* bias = (const float*)d_in[2];
  float* out = (float*)d_out;

  const bool use_ws = (d_ws != nullptr) && (ws_size >= WS_BYTES);
  if (use_ws) {
    u16* wsB = (u16*)d_ws;
    prep_w<<<E_EXP, 256, 0, stream>>>(W, wsB);
    gemm_gate<true><<<T_TOK / BM, 256, 0, stream>>>(
        x, W, wsB, bias, out, out + (size_t)T_TOK * K_TOP);
  } else {
    gemm_gate<false><<<T_TOK / BM, 256, 0, stream>>>(
        x, W, nullptr, bias, out, out + (size_t)T_TOK * K_TOP);
  }
}